// Round 7
// baseline (333.985 us; speedup 1.0000x reference)
//
#include <hip/hip_runtime.h>

// HybridFrequencyEncoder: fused Haar DWT (16,3,1024,1024 -> 4x half-res) + 8x8 DCT-II on LL.
// Output: [LL_dct | LH | HL | HH], each (16,3,512,512) fp32, concatenated flat.
//
// Roofline-probe design: maximal coalescing, minimal exposed non-memory cost.
// Tile: 16 input rows x 128 input cols (8 KB), 256 threads, 24576 blocks.
//   Phase 1: thread (hr=t>>5, cp=t&31) loads float4 from rows 2hr/2hr+1 at col 4cp
//            (per instr: 2x 512B fully-contiguous segments/wave). Haar in regs.
//            LH/HL/HH nontemporal 8B stores (256B contiguous per 32-lane group).
//            LL pair -> LDS M[8][68] (b64, 2-way max = free).
//   Phase 2: 64 threads (wave 0), one per 8x8-block-row: 2x ds_read_b128 (pad 68
//            -> 2-way max), row DCT with ALL-LITERAL coefficients (64 FMA),
//            2x ds_write_b128 to U.
//   Phase 3: thread (k=t>>5, cp=t&31): 8x ds_read_b64 of U columns (2-way max),
//            col DCT w/ Dm row from tiny LDS (broadcast reads), nt 8B store.
// No f64 cos: DCT matrix is a compile-time table (validated by R3 pass).

typedef float f32x2 __attribute__((ext_vector_type(2)));

#define NOUT ((size_t)48 * 512 * 512)   // elements per subband

#define C0 0.35355339059327376f
#define C1 0.49039264020161522f
#define C2 0.46193976625564337f
#define C3 0.41573480615127262f
#define C4 0.35355339059327376f
#define C5 0.27778511650980111f
#define C6 0.19134171618254489f
#define C7 0.09754516100806414f

__device__ __constant__ float DCT_TAB[64] = {
     C0,  C0,  C0,  C0,  C0,  C0,  C0,  C0,
     C1,  C3,  C5,  C7, -C7, -C5, -C3, -C1,
     C2,  C6, -C6, -C2, -C2, -C6,  C6,  C2,
     C3, -C7, -C1, -C5,  C5,  C1,  C7, -C3,
     C4, -C4, -C4,  C4,  C4, -C4, -C4,  C4,
     C5, -C1,  C7,  C3, -C3, -C7,  C1, -C5,
     C6, -C2,  C2, -C6, -C6,  C2, -C2,  C6,
     C7, -C5,  C3, -C1,  C1, -C3,  C5, -C7,
};

__global__ __launch_bounds__(256) void hfe_kernel(const float* __restrict__ x,
                                                  float* __restrict__ out) {
    static constexpr float DMc[8][8] = {
        { C0,  C0,  C0,  C0,  C0,  C0,  C0,  C0},
        { C1,  C3,  C5,  C7, -C7, -C5, -C3, -C1},
        { C2,  C6, -C6, -C2, -C2, -C6,  C6,  C2},
        { C3, -C7, -C1, -C5,  C5,  C1,  C7, -C3},
        { C4, -C4, -C4,  C4,  C4, -C4, -C4,  C4},
        { C5, -C1,  C7,  C3, -C3, -C7,  C1, -C5},
        { C6, -C2,  C2, -C6, -C6,  C2, -C2,  C6},
        { C7, -C5,  C3, -C1,  C1, -C3,  C5, -C7},
    };

    __shared__ float M[8][68];    // LL tile (stride 68 -> conflict-free b128/b64)
    __shared__ float U[8][68];    // after row pass
    __shared__ float Dm[8][8];    // coefficient rows for col pass

    const int t = threadIdx.x;
    if (t < 64) Dm[t >> 3][t & 7] = DCT_TAB[t];

    const int bid = blockIdx.x;
    const int bc  = bid >> 9;          // image 0..47 (512 tiles/image)
    const int rem = bid & 511;
    const int ty  = rem >> 3;          // 0..63 : 16-row input tile
    const int tx  = rem & 7;           // 0..7  : 128-col input tile

    const size_t img_in  = (size_t)bc * (1024 * 1024);
    const size_t img_out = (size_t)bc * (512 * 512);

    // ---------------- Phase 1: Haar ----------------
    const int hr = t >> 5;             // 0..7  LL row in tile
    const int cp = t & 31;             // 0..31 LL col-pair in tile

    const float* p0 = x + img_in + (size_t)(ty * 16 + hr * 2) * 1024 + tx * 128 + cp * 4;
    const float4 a = *(const float4*)(p0);
    const float4 b = *(const float4*)(p0 + 1024);

    const float s1 = a.x + a.y, d1 = a.x - a.y;
    const float s2 = b.x + b.y, d2 = b.x - b.y;
    const float s3 = a.z + a.w, d3 = a.z - a.w;
    const float s4 = b.z + b.w, d4 = b.z - b.w;

    const float ll0 = (s1 + s2) * 0.5f, lh0 = (s1 - s2) * 0.5f;
    const float hl0 = (d1 + d2) * 0.5f, hh0 = (d1 - d2) * 0.5f;
    const float ll1 = (s3 + s4) * 0.5f, lh1 = (s3 - s4) * 0.5f;
    const float hl1 = (d3 + d4) * 0.5f, hh1 = (d3 - d4) * 0.5f;

    const size_t hidx = img_out + (size_t)(ty * 8 + hr) * 512 + tx * 64 + cp * 2;
    __builtin_nontemporal_store((f32x2){lh0, lh1}, (f32x2*)(out + NOUT     + hidx));
    __builtin_nontemporal_store((f32x2){hl0, hl1}, (f32x2*)(out + 2 * NOUT + hidx));
    __builtin_nontemporal_store((f32x2){hh0, hh1}, (f32x2*)(out + 3 * NOUT + hidx));

    *(f32x2*)&M[hr][cp * 2] = (f32x2){ll0, ll1};

    __syncthreads();

    // ---------------- Phase 2: row DCT (literal coefficients) ----------------
    if (t < 64) {
        const int b8 = (t >> 3) * 8;   // block col offset 0,8,..,56
        const int r  = t & 7;          // LL row
        float m[8];
        *(float4*)&m[0] = *(const float4*)&M[r][b8];
        *(float4*)&m[4] = *(const float4*)&M[r][b8 + 4];
        float u[8];
#pragma unroll
        for (int l = 0; l < 8; ++l) {
            float acc = m[0] * DMc[l][0];
#pragma unroll
            for (int n = 1; n < 8; ++n) acc = fmaf(m[n], DMc[l][n], acc);
            u[l] = acc;
        }
        *(float4*)&U[r][b8]     = *(float4*)&u[0];
        *(float4*)&U[r][b8 + 4] = *(float4*)&u[4];
    }

    __syncthreads();

    // ---------------- Phase 3: col DCT ----------------
    const int k = t >> 5;              // 0..7 output row (within 8x8 blocks)
    float Dk[8];
#pragma unroll
    for (int m = 0; m < 8; ++m) Dk[m] = Dm[k][m];

    float o0 = 0.f, o1 = 0.f;
#pragma unroll
    for (int m = 0; m < 8; ++m) {
        const f32x2 um = *(const f32x2*)&U[m][cp * 2];
        o0 = fmaf(Dk[m], um.x, o0);
        o1 = fmaf(Dk[m], um.y, o1);
    }
    __builtin_nontemporal_store((f32x2){o0, o1}, (f32x2*)(out + hidx));
}

extern "C" void kernel_launch(void* const* d_in, const int* in_sizes, int n_in,
                              void* d_out, int out_size, void* d_ws, size_t ws_size,
                              hipStream_t stream) {
    const float* x = (const float*)d_in[0];
    float* out = (float*)d_out;
    // 48 images * 64 row-tiles * 8 col-tiles = 24576 blocks
    hfe_kernel<<<dim3(24576), dim3(256), 0, stream>>>(x, out);
}